// Round 10
// baseline (241.437 us; speedup 1.0000x reference)
//
#include <hip/hip_runtime.h>
#include <hip/hip_bf16.h>

// GraphSAGE 2-layer forward, MI355X. R10:
//  - wave-per-node aggregation: 4 edge-slots x 16 ch-groups per wave, 16 edges
//    in flight with per-lane predication (no cross-node divergence), cross-slot
//    reduction via shfl_xor(16/32).
//  - GEMM epilogue repacked through LDS -> dwordx4 stores (was 64 scalar
//    2B stores/lane) for h (bf16) and hp (fp8) outputs.

#define N_NODES 50000
#define IN_C    128
#define HID_C   256
#define OUT_C   128
#define N_EDGES 600000

// prep block partition: count first (latency-bound), then streaming
#define PB_CNT  2344                 // ceil(600000/256)
#define PB_W1   (PB_CNT + 256)       // 2600
#define PB_W2   (PB_W1 + 256)        // 2856
#define PB_X    (PB_W2 + 6250)       // 9106 total

typedef __attribute__((ext_vector_type(8))) short short8;   // 8 bf16 (16B)
typedef __attribute__((ext_vector_type(4))) float f32x4;
typedef __attribute__((ext_vector_type(2))) float f32x2;

__device__ __forceinline__ float bf2f(short s) {
    union { unsigned u; float f; } c;
    c.u = ((unsigned)(unsigned short)s) << 16;
    return c.f;
}
__device__ __forceinline__ unsigned f2fp8(float v) {
    return (unsigned)__builtin_amdgcn_cvt_pk_fp8_f32(v, v, 0, false) & 0xffu;
}
// accumulate 4 fp8 bytes (one u32) into a[0..3]
__device__ __forceinline__ void acc_fp8x4(float* a, unsigned u) {
    f32x2 lo = __builtin_amdgcn_cvt_pk_f32_fp8(u, false);
    f32x2 hi = __builtin_amdgcn_cvt_pk_f32_fp8(u, true);
    a[0] += lo[0]; a[1] += lo[1]; a[2] += hi[0]; a[3] += hi[1];
}

// ---------------- fused prep (+ degree count) ----------------
__global__ __launch_bounds__(256) void prep(
    const float* __restrict__ x, __hip_bfloat16* __restrict__ A1,
    const float* __restrict__ W1l, const float* __restrict__ W1r,
    const float* __restrict__ W2l, const float* __restrict__ W2r,
    __hip_bfloat16* __restrict__ W1t, __hip_bfloat16* __restrict__ W2t,
    const int* __restrict__ dstI, int* __restrict__ cnt) {
    int b = blockIdx.x;
    if (b < PB_CNT) {
        int e = b * 256 + threadIdx.x;
        if (e < N_EDGES) atomicAdd(&cnt[dstI[e]], 1);
    } else if (b < PB_W1) {
        int reg = b - PB_CNT;
        int half = reg >> 7;
        int t = (reg & 127) * 256 + threadIdx.x;
        int k = t >> 8, n = t & 255;
        const float* src = half ? W1r : W1l;
        W1t[n * 256 + half * 128 + k] = __float2bfloat16(src[t]);
    } else if (b < PB_W2) {
        int reg = b - PB_W1;
        int half = reg >> 7;
        int t = (reg & 127) * 256 + threadIdx.x;
        int k = t >> 7, n = t & 127;
        const float* src = half ? W2r : W2l;
        W2t[(size_t)(half * 128 + n) * 256 + k] = __float2bfloat16(src[t]);
    } else {
        int t = (b - PB_W2) * 256 + threadIdx.x;
        if (t >= N_NODES * 32) return;
        int row = t >> 5, c = (t & 31) * 4;
        float4 v = *(const float4*)(x + (size_t)row * 128 + c);
        __hip_bfloat16* d = A1 + (size_t)row * 256 + 128 + c;
        __hip_bfloat162 p0, p1;
        p0.x = __float2bfloat16(v.x); p0.y = __float2bfloat16(v.y);
        p1.x = __float2bfloat16(v.z); p1.y = __float2bfloat16(v.w);
        *(__hip_bfloat162*)d = p0;
        *(__hip_bfloat162*)(d + 2) = p1;
    }
}

// ---------------- CSR build ----------------
__global__ __launch_bounds__(256) void assign_offsets(
    const int* __restrict__ cnt, int* __restrict__ row_ptr,
    int* __restrict__ cursor, int* __restrict__ total, int n) {
    __shared__ int tmp[256];
    __shared__ int sbase;
    int t = threadIdx.x, g = blockIdx.x * 256 + t;
    int v = (g < n) ? cnt[g] : 0;
    tmp[t] = v; __syncthreads();
    for (int off = 1; off < 256; off <<= 1) {
        int u = (t >= off) ? tmp[t - off] : 0;
        __syncthreads();
        tmp[t] += u;
        __syncthreads();
    }
    if (t == 255) sbase = atomicAdd(total, tmp[255]);
    __syncthreads();
    if (g < n) {
        int e = sbase + tmp[t] - v;
        row_ptr[g] = e;
        cursor[g] = e;
    }
}

__global__ void fill_csr(const int* __restrict__ srcI, const int* __restrict__ dstI,
                         int* __restrict__ cursor, int* __restrict__ col, int E) {
    int e = blockIdx.x * blockDim.x + threadIdx.x;
    if (e < E) {
        int pos = atomicAdd(&cursor[dstI[e]], 1);
        col[pos] = srcI[e];
    }
}

// ---------------- layer-1 mean aggregation (bf16, wave per node) ----------------
// lane = (slot 0..3) * 16 + (ch-group 0..15); 16 edges in flight per iter.
__global__ __launch_bounds__(256) void aggregate_bf16(
    const __hip_bfloat16* __restrict__ feat, int featStride,
    const int* __restrict__ row_ptr, const int* __restrict__ deg,
    const int* __restrict__ col,
    __hip_bfloat16* __restrict__ outp, int outStride, int nNodes) {
    int node = (blockIdx.x * 256 + threadIdx.x) >> 6;
    if (node >= nNodes) return;
    int lane = threadIdx.x & 63;
    int slot = lane >> 4, sl = lane & 15;
    int beg = row_ptr[node];
    int d   = deg[node];
    const __hip_bfloat16* base = feat + sl * 8;
    float a[8];
    #pragma unroll
    for (int c = 0; c < 8; ++c) a[c] = 0.f;

    for (int j = 0; j < d; j += 16) {
        int e0 = j + slot, e1 = j + 4 + slot, e2 = j + 8 + slot, e3 = j + 12 + slot;
        int s0 = col[beg + min(e0, d - 1)];
        int s1 = col[beg + min(e1, d - 1)];
        int s2 = col[beg + min(e2, d - 1)];
        int s3 = col[beg + min(e3, d - 1)];
        short8 v0 = *(const short8*)(base + (size_t)s0 * featStride);
        short8 v1 = *(const short8*)(base + (size_t)s1 * featStride);
        short8 v2 = *(const short8*)(base + (size_t)s2 * featStride);
        short8 v3 = *(const short8*)(base + (size_t)s3 * featStride);
        bool b0 = e0 < d, b1 = e1 < d, b2 = e2 < d, b3 = e3 < d;
        #pragma unroll
        for (int c = 0; c < 8; ++c) {
            float f0 = b0 ? bf2f(v0[c]) : 0.f;
            float f1 = b1 ? bf2f(v1[c]) : 0.f;
            float f2 = b2 ? bf2f(v2[c]) : 0.f;
            float f3 = b3 ? bf2f(v3[c]) : 0.f;
            a[c] += (f0 + f1) + (f2 + f3);
        }
    }
    // cross-slot reduction (slots 0..3 -> slot 0 lanes)
    #pragma unroll
    for (int c = 0; c < 8; ++c) {
        a[c] += __shfl_xor(a[c], 16, 64);
        a[c] += __shfl_xor(a[c], 32, 64);
    }
    if (slot == 0) {
        float inv = 1.f / (float)max(d, 1);
        __hip_bfloat16* o = outp + (size_t)node * outStride + sl * 8;
        short8 q;
        #pragma unroll
        for (int c = 0; c < 8; ++c) {
            union { __hip_bfloat16 b; short s; } cv;
            cv.b = __float2bfloat16(a[c] * inv);
            q[c] = cv.s;
        }
        *(short8*)o = q;
    }
}

// ---------------- final aggregation (fp8, wave per node) ----------------
__global__ __launch_bounds__(256) void aggregate_fp8_final(
    const unsigned char* __restrict__ feat,   // [n][128] fp8 e4m3
    const int* __restrict__ row_ptr, const int* __restrict__ deg,
    const int* __restrict__ col,
    float* __restrict__ outp, const float* __restrict__ pre, int nNodes) {
    int node = (blockIdx.x * 256 + threadIdx.x) >> 6;
    if (node >= nNodes) return;
    int lane = threadIdx.x & 63;
    int slot = lane >> 4, sl = lane & 15;
    int beg = row_ptr[node];
    int d   = deg[node];
    const unsigned char* base = feat + sl * 8;
    float a[8];
    #pragma unroll
    for (int c = 0; c < 8; ++c) a[c] = 0.f;

    for (int j = 0; j < d; j += 16) {
        int e0 = j + slot, e1 = j + 4 + slot, e2 = j + 8 + slot, e3 = j + 12 + slot;
        int s0 = col[beg + min(e0, d - 1)];
        int s1 = col[beg + min(e1, d - 1)];
        int s2 = col[beg + min(e2, d - 1)];
        int s3 = col[beg + min(e3, d - 1)];
        uint2 v0 = *(const uint2*)(base + (size_t)s0 * 128);
        uint2 v1 = *(const uint2*)(base + (size_t)s1 * 128);
        uint2 v2 = *(const uint2*)(base + (size_t)s2 * 128);
        uint2 v3 = *(const uint2*)(base + (size_t)s3 * 128);
        if (e0 >= d) { v0.x = 0u; v0.y = 0u; }   // fp8 0x00 == 0.0
        if (e1 >= d) { v1.x = 0u; v1.y = 0u; }
        if (e2 >= d) { v2.x = 0u; v2.y = 0u; }
        if (e3 >= d) { v3.x = 0u; v3.y = 0u; }
        acc_fp8x4(a,     v0.x); acc_fp8x4(a,     v1.x);
        acc_fp8x4(a,     v2.x); acc_fp8x4(a,     v3.x);
        acc_fp8x4(a + 4, v0.y); acc_fp8x4(a + 4, v1.y);
        acc_fp8x4(a + 4, v2.y); acc_fp8x4(a + 4, v3.y);
    }
    #pragma unroll
    for (int c = 0; c < 8; ++c) {
        a[c] += __shfl_xor(a[c], 16, 64);
        a[c] += __shfl_xor(a[c], 32, 64);
    }
    if (slot == 0) {
        float inv = 1.f / (float)max(d, 1);
        const float* pp = pre + (size_t)node * 128 + sl * 8;
        float* op = outp + (size_t)node * 128 + sl * 8;
        float4 p0 = *(const float4*)pp;
        float4 p1 = *(const float4*)(pp + 4);
        *(float4*)op       = make_float4(a[0] * inv + p0.x, a[1] * inv + p0.y,
                                         a[2] * inv + p0.z, a[3] * inv + p0.w);
        *(float4*)(op + 4) = make_float4(a[4] * inv + p1.x, a[5] * inv + p1.y,
                                         a[6] * inv + p1.z, a[7] * inv + p1.w);
    }
}

// ---------------- bf16 MFMA GEMM ----------------
// mode 0 (layer1): outBf = relu(A@Bt^T + bias), row stride 256, col base nb.
//                  Epilogue repacked via LDS -> dwordx4 stores.
// mode 1 (layer2 fused, grid.y=2):
//   y==0: outF8 = fp8(A@W2l^T) [50000][128], LDS-repacked stores.
//   y==1: outF  = A@W2r^T + bias (fp32), scalar dword stores.

#define GBM 128
#define GBN 128
#define GBK 64

__device__ __forceinline__ void gload16(const void* g, void* l) {
    typedef const __attribute__((address_space(1))) unsigned int* gp_t;
    typedef __attribute__((address_space(3))) unsigned int* lp_t;
    __builtin_amdgcn_global_load_lds((gp_t)g, (lp_t)l, 16, 0, 0);
}

__global__ __launch_bounds__(256) void gemm_mfma(
    const __hip_bfloat16* __restrict__ A, int lda,
    const __hip_bfloat16* __restrict__ Bt,
    const float* __restrict__ bias,
    __hip_bfloat16* __restrict__ outBf,
    unsigned char* __restrict__ outF8,
    float* __restrict__ outF,
    int M, int K, int mode) {
    __shared__ __hip_bfloat16 sBuf[GBM * GBK * 2];   // 32 KB: A-stage | B-stage; reused by epilogue
    __hip_bfloat16* Als = sBuf;
    __hip_bfloat16* Bls = sBuf + GBM * GBK;

    int tid  = threadIdx.x;
    int wave = tid >> 6, lane = tid & 63;
    int wm = wave >> 1, wn = wave & 1;
    int mb = blockIdx.x * GBM, nb = blockIdx.y * GBN;

    int srow_base = wave * 32;
    int lrow = lane >> 3;
    int pch  = lane & 7;

    f32x4 acc[4][4];
    #pragma unroll
    for (int i = 0; i < 4; ++i)
        #pragma unroll
        for (int j = 0; j < 4; ++j)
            acc[i][j] = (f32x4){0.f, 0.f, 0.f, 0.f};

    for (int kt = 0; kt < K; kt += GBK) {
        #pragma unroll
        for (int t = 0; t < 4; ++t) {
            int rloc = srow_base + t * 8 + lrow;
            int lch  = pch ^ (rloc & 7);
            int ga_row = mb + rloc; if (ga_row >= M) ga_row = M - 1;
            const __hip_bfloat16* ga = A + (size_t)ga_row * lda + kt + lch * 8;
            gload16(ga, &Als[(srow_base + t * 8) * GBK]);
            const __hip_bfloat16* gb = Bt + (size_t)(nb + rloc) * K + kt + lch * 8;
            gload16(gb, &Bls[(srow_base + t * 8) * GBK]);
        }
        __syncthreads();

        #pragma unroll
        for (int ks = 0; ks < GBK; ks += 32) {
            int chunkL = (ks >> 3) + (lane >> 4);
            short8 af[4], bf[4];
            #pragma unroll
            for (int i = 0; i < 4; ++i) {
                int row = wm * 64 + i * 16 + (lane & 15);
                int pc  = chunkL ^ (row & 7);
                af[i] = *(const short8*)&Als[row * GBK + pc * 8];
            }
            #pragma unroll
            for (int j = 0; j < 4; ++j) {
                int row = wn * 64 + j * 16 + (lane & 15);
                int pc  = chunkL ^ (row & 7);
                bf[j] = *(const short8*)&Bls[row * GBK + pc * 8];
            }
            #pragma unroll
            for (int i = 0; i < 4; ++i)
                #pragma unroll
                for (int j = 0; j < 4; ++j)
                    acc[i][j] = __builtin_amdgcn_mfma_f32_16x16x32_bf16(
                        af[i], bf[j], acc[i][j], 0, 0, 0);
        }
        __syncthreads();
    }

    // epilogue: C/D layout col=lane&15, row=(lane>>4)*4+reg
    int cn[4];
    float bc[4];
    #pragma unroll
    for (int j = 0; j < 4; ++j) {
        cn[j] = wn * 64 + j * 16 + (lane & 15);
        bc[j] = 0.f;
    }
    if (mode == 0) {
        // relu(acc + bias) -> LDS bf16 [128][128] -> dwordx4 stores
        #pragma unroll
        for (int j = 0; j < 4; ++j) bc[j] = bias[nb + cn[j]];
        #pragma unroll
        for (int i = 0; i < 4; ++i)
            #pragma unroll
            for (int r = 0; r < 4; ++r) {
                int lr = wm * 64 + i * 16 + (lane >> 4) * 4 + r;
                #pragma unroll
                for (int j = 0; j < 4; ++j) {
                    float v = fmaxf(acc[i][j][r] + bc[j], 0.f);
                    sBuf[lr * 128 + cn[j]] = __float2bfloat16(v);
                }
            }
        __syncthreads();
        #pragma unroll
        for (int it = 0; it < 8; ++it) {
            int chunk = it * 256 + tid;          // 0..2047, 16B each
            int lr  = chunk >> 4;                // 16 chunks per 256B row
            int lcB = (chunk & 15) * 16;
            int grow = mb + lr;
            if (grow < M)
                *(float4*)((char*)outBf + (size_t)grow * 512 + nb * 2 + lcB) =
                    *(const float4*)((const char*)sBuf + lr * 256 + lcB);
        }
    } else if (blockIdx.y == 0) {
        // fp8(acc) -> LDS [128][128] bytes -> dwordx4 stores
        unsigned char* s8 = (unsigned char*)sBuf;
        #pragma unroll
        for (int i = 0; i < 4; ++i)
            #pragma unroll
            for (int r = 0; r < 4; ++r) {
                int lr = wm * 64 + i * 16 + (lane >> 4) * 4 + r;
                #pragma unroll
                for (int j = 0; j < 4; ++j)
                    s8[lr * 128 + cn[j]] = (unsigned char)f2fp8(acc[i][j][r]);
            }
        __syncthreads();
        #pragma unroll
        for (int it = 0; it < 4; ++it) {
            int chunk = it * 256 + tid;          // 0..1023, 16B each
            int lr  = chunk >> 3;                // 8 chunks per 128B row
            int lcB = (chunk & 7) * 16;
            int grow = mb + lr;
            if (grow < M)
                *(float4*)(outF8 + (size_t)grow * 128 + lcB) =
                    *(const float4*)(s8 + lr * 128 + lcB);
        }
    } else {
        #pragma unroll
        for (int j = 0; j < 4; ++j) bc[j] = bias[cn[j]];
        #pragma unroll
        for (int i = 0; i < 4; ++i)
            #pragma unroll
            for (int r = 0; r < 4; ++r) {
                int row = mb + wm * 64 + i * 16 + (lane >> 4) * 4 + r;
                if (row >= M) continue;
                #pragma unroll
                for (int j = 0; j < 4; ++j)
                    outF[(size_t)row * 128 + cn[j]] = acc[i][j][r] + bc[j];
            }
    }
}

extern "C" void kernel_launch(void* const* d_in, const int* in_sizes, int n_in,
                              void* d_out, int out_size, void* d_ws, size_t ws_size,
                              hipStream_t stream) {
    const float* x    = (const float*)d_in[0];
    const int*   ei   = (const int*)d_in[1];
    const float* W1l  = (const float*)d_in[2];
    const float* b1   = (const float*)d_in[3];
    const float* W1r  = (const float*)d_in[4];
    const float* W2l  = (const float*)d_in[5];
    const float* b2   = (const float*)d_in[6];
    const float* W2r  = (const float*)d_in[7];
    float* out = (float*)d_out;

    const int E = N_EDGES;
    const int N = N_NODES;
    const int* srcI = ei;
    const int* dstI = ei + E;

    // workspace layout (bytes)
    char* w = (char*)d_ws;
    int*            cnt     = (int*)(w + 0);                   // 200000
    int*            total   = (int*)(w + 200000);              // 4 (memset with cnt)
    int*            row_ptr = (int*)(w + 204800);              // 200000
    int*            col     = (int*)(w + 409600);              // 2400000
    __hip_bfloat16* W1t     = (__hip_bfloat16*)(w + 2818048);  // [256][256]
    __hip_bfloat16* W2t     = (__hip_bfloat16*)(w + 2949120);  // [256][256]
    int*            cursor  = (int*)(w + 3080192);             // 200000
    __hip_bfloat16* A1      = (__hip_bfloat16*)(w + 3280896);  // [50000][256]
    __hip_bfloat16* h_bf    = (__hip_bfloat16*)(w + 28880896); // [50000][256]
    unsigned char*  hp_f8   = (unsigned char*)(w + 54480896);  // [50000][128] fp8
    float*          pre     = (float*)(w + 67280896);          // [50000][128] fp32

    // ---- zero cnt+total, then fused prep (+degree count) ----
    hipMemsetAsync(cnt, 0, 200004, stream);
    prep<<<PB_X, 256, 0, stream>>>(x, A1, W1l, W1r, W2l, W2r, W1t, W2t, dstI, cnt);

    // ---- CSR build ----
    assign_offsets<<<(N + 255) / 256, 256, 0, stream>>>(cnt, row_ptr, cursor, total, N);
    fill_csr<<<(E + 255) / 256, 256, 0, stream>>>(srcI, dstI, cursor, col, E);

    // ---- layer 1 (wave per node: 4 nodes per 256-thr block) ----
    aggregate_bf16<<<(N + 3) / 4, 256, 0, stream>>>(
        A1 + 128, 256, row_ptr, cnt, col, A1, 256, N);
    {
        dim3 grid((N + GBM - 1) / GBM, HID_C / GBN);
        gemm_mfma<<<grid, 256, 0, stream>>>(A1, 256, W1t, b1,
                                            h_bf, nullptr, nullptr, N, 256, 0);
    }

    // ---- layer 2 fused projection (y0 -> hp fp8, y1 -> pre fp32) ----
    {
        dim3 grid((N + GBM - 1) / GBM, 2);
        gemm_mfma<<<grid, 256, 0, stream>>>(h_bf, 256, W2t, b2,
                                            nullptr, hp_f8, pre, N, 256, 1);
    }
    // ---- final: out = pre + mean(hp) ----
    aggregate_fp8_final<<<(N + 3) / 4, 256, 0, stream>>>(
        hp_f8, row_ptr, cnt, col, out, pre, N);
}

// Round 11
// 234.795 us; speedup vs baseline: 1.0283x; 1.0283x over previous
//
#include <hip/hip_runtime.h>
#include <hip/hip_bf16.h>

// GraphSAGE 2-layer forward, MI355X. R11 = R9 aggregators (proven) +
// LDS-repacked GEMM epilogue with conflict-aware strides (isolated A/B of
// the epilogue change from R10's regressed bundle).

#define N_NODES 50000
#define IN_C    128
#define HID_C   256
#define OUT_C   128
#define N_EDGES 600000

// prep block partition: count first (latency-bound), then streaming
#define PB_CNT  2344                 // ceil(600000/256)
#define PB_W1   (PB_CNT + 256)       // 2600
#define PB_W2   (PB_W1 + 256)        // 2856
#define PB_X    (PB_W2 + 6250)       // 9106 total

typedef __attribute__((ext_vector_type(8))) short short8;   // 8 bf16 (16B)
typedef __attribute__((ext_vector_type(4))) float f32x4;
typedef __attribute__((ext_vector_type(2))) float f32x2;

__device__ __forceinline__ float bf2f(short s) {
    union { unsigned u; float f; } c;
    c.u = ((unsigned)(unsigned short)s) << 16;
    return c.f;
}
__device__ __forceinline__ unsigned f2fp8(float v) {
    return (unsigned)__builtin_amdgcn_cvt_pk_fp8_f32(v, v, 0, false) & 0xffu;
}
// accumulate 4 fp8 bytes (one u32) into a[0..3]
__device__ __forceinline__ void acc_fp8x4(float* a, unsigned u) {
    f32x2 lo = __builtin_amdgcn_cvt_pk_f32_fp8(u, false);
    f32x2 hi = __builtin_amdgcn_cvt_pk_f32_fp8(u, true);
    a[0] += lo[0]; a[1] += lo[1]; a[2] += hi[0]; a[3] += hi[1];
}

// ---------------- fused prep (+ degree count) ----------------
__global__ __launch_bounds__(256) void prep(
    const float* __restrict__ x, __hip_bfloat16* __restrict__ A1,
    const float* __restrict__ W1l, const float* __restrict__ W1r,
    const float* __restrict__ W2l, const float* __restrict__ W2r,
    __hip_bfloat16* __restrict__ W1t, __hip_bfloat16* __restrict__ W2t,
    const int* __restrict__ dstI, int* __restrict__ cnt) {
    int b = blockIdx.x;
    if (b < PB_CNT) {
        int e = b * 256 + threadIdx.x;
        if (e < N_EDGES) atomicAdd(&cnt[dstI[e]], 1);
    } else if (b < PB_W1) {
        int reg = b - PB_CNT;
        int half = reg >> 7;
        int t = (reg & 127) * 256 + threadIdx.x;
        int k = t >> 8, n = t & 255;
        const float* src = half ? W1r : W1l;
        W1t[n * 256 + half * 128 + k] = __float2bfloat16(src[t]);
    } else if (b < PB_W2) {
        int reg = b - PB_W1;
        int half = reg >> 7;
        int t = (reg & 127) * 256 + threadIdx.x;
        int k = t >> 7, n = t & 127;
        const float* src = half ? W2r : W2l;
        W2t[(size_t)(half * 128 + n) * 256 + k] = __float2bfloat16(src[t]);
    } else {
        int t = (b - PB_W2) * 256 + threadIdx.x;
        if (t >= N_NODES * 32) return;
        int row = t >> 5, c = (t & 31) * 4;
        float4 v = *(const float4*)(x + (size_t)row * 128 + c);
        __hip_bfloat16* d = A1 + (size_t)row * 256 + 128 + c;
        __hip_bfloat162 p0, p1;
        p0.x = __float2bfloat16(v.x); p0.y = __float2bfloat16(v.y);
        p1.x = __float2bfloat16(v.z); p1.y = __float2bfloat16(v.w);
        *(__hip_bfloat162*)d = p0;
        *(__hip_bfloat162*)(d + 2) = p1;
    }
}

// ---------------- CSR build ----------------
__global__ __launch_bounds__(256) void assign_offsets(
    const int* __restrict__ cnt, int* __restrict__ row_ptr,
    int* __restrict__ cursor, int* __restrict__ total, int n) {
    __shared__ int tmp[256];
    __shared__ int sbase;
    int t = threadIdx.x, g = blockIdx.x * 256 + t;
    int v = (g < n) ? cnt[g] : 0;
    tmp[t] = v; __syncthreads();
    for (int off = 1; off < 256; off <<= 1) {
        int u = (t >= off) ? tmp[t - off] : 0;
        __syncthreads();
        tmp[t] += u;
        __syncthreads();
    }
    if (t == 255) sbase = atomicAdd(total, tmp[255]);
    __syncthreads();
    if (g < n) {
        int e = sbase + tmp[t] - v;
        row_ptr[g] = e;
        cursor[g] = e;
    }
}

__global__ void fill_csr(const int* __restrict__ srcI, const int* __restrict__ dstI,
                         int* __restrict__ cursor, int* __restrict__ col, int E) {
    int e = blockIdx.x * blockDim.x + threadIdx.x;
    if (e < E) {
        int pos = atomicAdd(&cursor[dstI[e]], 1);
        col[pos] = srcI[e];
    }
}

// ---------------- layer-1 mean aggregation (bf16 gather, R9 form) ----------------
__global__ __launch_bounds__(256) void aggregate_bf16(
    const __hip_bfloat16* __restrict__ feat, int featStride,
    const int* __restrict__ row_ptr, const int* __restrict__ deg,
    const int* __restrict__ col,
    __hip_bfloat16* __restrict__ outp, int outStride, int nNodes) {
    int node = blockIdx.x * 16 + (threadIdx.x >> 4);
    int sl   = threadIdx.x & 15;
    if (node >= nNodes) return;
    int beg = row_ptr[node];
    int d   = deg[node];
    const __hip_bfloat16* base = feat + sl * 8;
    float a[8];
    #pragma unroll
    for (int c = 0; c < 8; ++c) a[c] = 0.f;

    short8 v0, v1, v2, v3;
    int j = 0;
    if (d >= 4) {
        int s0 = col[beg + 0], s1 = col[beg + 1];
        int s2 = col[beg + 2], s3 = col[beg + 3];
        v0 = *(const short8*)(base + (size_t)s0 * featStride);
        v1 = *(const short8*)(base + (size_t)s1 * featStride);
        v2 = *(const short8*)(base + (size_t)s2 * featStride);
        v3 = *(const short8*)(base + (size_t)s3 * featStride);
        for (; j + 8 <= d; j += 4) {
            int t0 = col[beg + j + 4], t1 = col[beg + j + 5];
            int t2 = col[beg + j + 6], t3 = col[beg + j + 7];
            short8 w0 = *(const short8*)(base + (size_t)t0 * featStride);
            short8 w1 = *(const short8*)(base + (size_t)t1 * featStride);
            short8 w2 = *(const short8*)(base + (size_t)t2 * featStride);
            short8 w3 = *(const short8*)(base + (size_t)t3 * featStride);
            #pragma unroll
            for (int c = 0; c < 8; ++c)
                a[c] += (bf2f(v0[c]) + bf2f(v1[c])) + (bf2f(v2[c]) + bf2f(v3[c]));
            v0 = w0; v1 = w1; v2 = w2; v3 = w3;
        }
        #pragma unroll
        for (int c = 0; c < 8; ++c)
            a[c] += (bf2f(v0[c]) + bf2f(v1[c])) + (bf2f(v2[c]) + bf2f(v3[c]));
        j += 4;
    }
    int rem = d - j;
    if (rem > 0) {
        int s0 = col[beg + j];
        int s1 = (rem > 1) ? col[beg + j + 1] : s0;
        int s2 = (rem > 2) ? col[beg + j + 2] : s0;
        short8 t0 = *(const short8*)(base + (size_t)s0 * featStride);
        short8 t1 = *(const short8*)(base + (size_t)s1 * featStride);
        short8 t2 = *(const short8*)(base + (size_t)s2 * featStride);
        #pragma unroll
        for (int c = 0; c < 8; ++c) a[c] += bf2f(t0[c]);
        if (rem > 1) {
            #pragma unroll
            for (int c = 0; c < 8; ++c) a[c] += bf2f(t1[c]);
        }
        if (rem > 2) {
            #pragma unroll
            for (int c = 0; c < 8; ++c) a[c] += bf2f(t2[c]);
        }
    }

    float inv = 1.f / (float)max(d, 1);
    __hip_bfloat16* o = outp + (size_t)node * outStride + sl * 8;
    short8 q;
    #pragma unroll
    for (int c = 0; c < 8; ++c) {
        union { __hip_bfloat16 b; short s; } cv;
        cv.b = __float2bfloat16(a[c] * inv);
        q[c] = cv.s;
    }
    *(short8*)o = q;
}

// ---------------- final aggregation (fp8 gather, R9 form) ----------------
__global__ __launch_bounds__(256) void aggregate_fp8_final(
    const unsigned char* __restrict__ feat,   // [n][128] fp8 e4m3
    const int* __restrict__ row_ptr, const int* __restrict__ deg,
    const int* __restrict__ col,
    float* __restrict__ outp, const float* __restrict__ pre, int nNodes) {
    int node = blockIdx.x * 16 + (threadIdx.x >> 4);
    int sl   = threadIdx.x & 15;
    if (node >= nNodes) return;
    int beg = row_ptr[node];
    int d   = deg[node];
    const unsigned char* base = feat + sl * 8;
    float a[8];
    #pragma unroll
    for (int c = 0; c < 8; ++c) a[c] = 0.f;

    uint2 v0, v1, v2, v3;
    int j = 0;
    if (d >= 4) {
        int s0 = col[beg + 0], s1 = col[beg + 1];
        int s2 = col[beg + 2], s3 = col[beg + 3];
        v0 = *(const uint2*)(base + (size_t)s0 * 128);
        v1 = *(const uint2*)(base + (size_t)s1 * 128);
        v2 = *(const uint2*)(base + (size_t)s2 * 128);
        v3 = *(const uint2*)(base + (size_t)s3 * 128);
        for (; j + 8 <= d; j += 4) {
            int t0 = col[beg + j + 4], t1 = col[beg + j + 5];
            int t2 = col[beg + j + 6], t3 = col[beg + j + 7];
            uint2 w0 = *(const uint2*)(base + (size_t)t0 * 128);
            uint2 w1 = *(const uint2*)(base + (size_t)t1 * 128);
            uint2 w2 = *(const uint2*)(base + (size_t)t2 * 128);
            uint2 w3 = *(const uint2*)(base + (size_t)t3 * 128);
            acc_fp8x4(a,     v0.x); acc_fp8x4(a,     v1.x);
            acc_fp8x4(a,     v2.x); acc_fp8x4(a,     v3.x);
            acc_fp8x4(a + 4, v0.y); acc_fp8x4(a + 4, v1.y);
            acc_fp8x4(a + 4, v2.y); acc_fp8x4(a + 4, v3.y);
            v0 = w0; v1 = w1; v2 = w2; v3 = w3;
        }
        acc_fp8x4(a,     v0.x); acc_fp8x4(a,     v1.x);
        acc_fp8x4(a,     v2.x); acc_fp8x4(a,     v3.x);
        acc_fp8x4(a + 4, v0.y); acc_fp8x4(a + 4, v1.y);
        acc_fp8x4(a + 4, v2.y); acc_fp8x4(a + 4, v3.y);
        j += 4;
    }
    for (; j < d; ++j) {
        uint2 v = *(const uint2*)(base + (size_t)col[beg + j] * 128);
        acc_fp8x4(a, v.x);
        acc_fp8x4(a + 4, v.y);
    }

    float inv = 1.f / (float)max(d, 1);
    const float* pp = pre + (size_t)node * 128 + sl * 8;
    float* op = outp + (size_t)node * 128 + sl * 8;
    float4 p0 = *(const float4*)pp;
    float4 p1 = *(const float4*)(pp + 4);
    *(float4*)op       = make_float4(a[0] * inv + p0.x, a[1] * inv + p0.y,
                                     a[2] * inv + p0.z, a[3] * inv + p0.w);
    *(float4*)(op + 4) = make_float4(a[4] * inv + p1.x, a[5] * inv + p1.y,
                                     a[6] * inv + p1.z, a[7] * inv + p1.w);
}

// ---------------- bf16 MFMA GEMM ----------------
// mode 0 (layer1): outBf = relu(A@Bt^T + bias), row stride 256 bf16.
//   Epilogue: scatter to LDS (stride 132 bf16 -> quad rows on distinct bank
//   groups, 2-way max) then 8 coalesced dwordx4 streams.
// mode 1 (layer2 fused, grid.y=2):
//   y==0: outF8 = fp8(A@W2l^T) [50000][128]; LDS stride 136 B, 4 dwordx4 streams.
//   y==1: outF  = A@W2r^T + bias (fp32), scalar dword stores.

#define GBM 128
#define GBN 128
#define GBK 64
#define EP_STRIDE_BF 132     // bf16 elems: 264 B = 66 dw == 2 (mod 32)
#define EP_STRIDE_F8 136     // bytes: 34 dw == 2 (mod 32)

__device__ __forceinline__ void gload16(const void* g, void* l) {
    typedef const __attribute__((address_space(1))) unsigned int* gp_t;
    typedef __attribute__((address_space(3))) unsigned int* lp_t;
    __builtin_amdgcn_global_load_lds((gp_t)g, (lp_t)l, 16, 0, 0);
}

__global__ __launch_bounds__(256) void gemm_mfma(
    const __hip_bfloat16* __restrict__ A, int lda,
    const __hip_bfloat16* __restrict__ Bt,
    const float* __restrict__ bias,
    __hip_bfloat16* __restrict__ outBf,
    unsigned char* __restrict__ outF8,
    float* __restrict__ outF,
    int M, int K, int mode) {
    // 34 KB: [staging A 16K | staging B 16K]; epilogue aliases whole buffer
    __shared__ char sm[GBM * EP_STRIDE_BF * 2];
    __hip_bfloat16* Als = (__hip_bfloat16*)sm;
    __hip_bfloat16* Bls = (__hip_bfloat16*)(sm + GBM * GBK * 2);

    int tid  = threadIdx.x;
    int wave = tid >> 6, lane = tid & 63;
    int wm = wave >> 1, wn = wave & 1;
    int mb = blockIdx.x * GBM, nb = blockIdx.y * GBN;

    int srow_base = wave * 32;
    int lrow = lane >> 3;
    int pch  = lane & 7;

    f32x4 acc[4][4];
    #pragma unroll
    for (int i = 0; i < 4; ++i)
        #pragma unroll
        for (int j = 0; j < 4; ++j)
            acc[i][j] = (f32x4){0.f, 0.f, 0.f, 0.f};

    for (int kt = 0; kt < K; kt += GBK) {
        #pragma unroll
        for (int t = 0; t < 4; ++t) {
            int rloc = srow_base + t * 8 + lrow;
            int lch  = pch ^ (rloc & 7);
            int ga_row = mb + rloc; if (ga_row >= M) ga_row = M - 1;
            const __hip_bfloat16* ga = A + (size_t)ga_row * lda + kt + lch * 8;
            gload16(ga, &Als[(srow_base + t * 8) * GBK]);
            const __hip_bfloat16* gb = Bt + (size_t)(nb + rloc) * K + kt + lch * 8;
            gload16(gb, &Bls[(srow_base + t * 8) * GBK]);
        }
        __syncthreads();

        #pragma unroll
        for (int ks = 0; ks < GBK; ks += 32) {
            int chunkL = (ks >> 3) + (lane >> 4);
            short8 af[4], bf[4];
            #pragma unroll
            for (int i = 0; i < 4; ++i) {
                int row = wm * 64 + i * 16 + (lane & 15);
                int pc  = chunkL ^ (row & 7);
                af[i] = *(const short8*)&Als[row * GBK + pc * 8];
            }
            #pragma unroll
            for (int j = 0; j < 4; ++j) {
                int row = wn * 64 + j * 16 + (lane & 15);
                int pc  = chunkL ^ (row & 7);
                bf[j] = *(const short8*)&Bls[row * GBK + pc * 8];
            }
            #pragma unroll
            for (int i = 0; i < 4; ++i)
                #pragma unroll
                for (int j = 0; j < 4; ++j)
                    acc[i][j] = __builtin_amdgcn_mfma_f32_16x16x32_bf16(
                        af[i], bf[j], acc[i][j], 0, 0, 0);
        }
        __syncthreads();   // also guards epilogue's LDS reuse
    }

    // epilogue: C/D layout col=lane&15, row=(lane>>4)*4+reg
    int cn[4];
    float bc[4];
    #pragma unroll
    for (int j = 0; j < 4; ++j) {
        cn[j] = wn * 64 + j * 16 + (lane & 15);
        bc[j] = 0.f;
    }
    if (mode == 0) {
        // relu(acc+bias) -> LDS bf16 [128][EP_STRIDE_BF] -> dwordx4 streams
        __hip_bfloat16* sb = (__hip_bfloat16*)sm;
        #pragma unroll
        for (int j = 0; j < 4; ++j) bc[j] = bias[nb + cn[j]];
        #pragma unroll
        for (int i = 0; i < 4; ++i)
            #pragma unroll
            for (int r = 0; r < 4; ++r) {
                int lr = wm * 64 + i * 16 + (lane >> 4) * 4 + r;
                #pragma unroll
                for (int j = 0; j < 4; ++j)
                    sb[lr * EP_STRIDE_BF + cn[j]] =
                        __float2bfloat16(fmaxf(acc[i][j][r] + bc[j], 0.f));
            }
        __syncthreads();
        #pragma unroll
        for (int it = 0; it < 8; ++it) {
            int chunk = it * 256 + tid;          // 0..2047, 16B each
            int lr  = chunk >> 4;                // 16 chunks per 256B data row
            int lcB = (chunk & 15) * 16;
            int grow = mb + lr;
            if (grow < M)
                *(float4*)((char*)outBf + (size_t)grow * 512 + nb * 2 + lcB) =
                    *(const float4*)((const char*)sb + lr * (EP_STRIDE_BF * 2) + lcB);
        }
    } else if (blockIdx.y == 0) {
        // fp8(acc) -> LDS [128][EP_STRIDE_F8] bytes -> dwordx4 streams
        unsigned char* s8 = (unsigned char*)sm;
        #pragma unroll
        for (int i = 0; i < 4; ++i)
            #pragma unroll
            for (int r = 0; r < 4; ++r) {
                int lr = wm * 64 + i * 16 + (lane >> 4) * 4 + r;
                #pragma unroll
                for (int j = 0; j < 4; ++j)
                    s8[lr * EP_STRIDE_F8 + cn[j]] = (unsigned char)f2fp8(acc[i][j][r]);
            }
        __syncthreads();
        #pragma unroll
        for (int it = 0; it < 4; ++it) {
            int chunk = it * 256 + tid;          // 0..1023, 16B each
            int lr  = chunk >> 3;                // 8 chunks per 128B data row
            int lcB = (chunk & 7) * 16;
            int grow = mb + lr;
            if (grow < M)
                *(float4*)(outF8 + (size_t)grow * 128 + lcB) =
                    *(const float4*)(s8 + lr * EP_STRIDE_F8 + lcB);
        }
    } else {
        #pragma unroll
        for (int j = 0; j < 4; ++j) bc[j] = bias[cn[j]];
        #pragma unroll
        for (int i = 0; i < 4; ++i)
            #pragma unroll
            for (int r = 0; r < 4; ++r) {
                int row = mb + wm * 64 + i * 16 + (lane >> 4) * 4 + r;
                if (row >= M) continue;
                #pragma unroll
                for (int j = 0; j < 4; ++j)
                    outF[(size_t)row * 128 + cn[j]] = acc[i][j][r] + bc[j];
            }
    }
}

extern "C" void kernel_launch(void* const* d_in, const int* in_sizes, int n_in,
                              void* d_out, int out_size, void* d_ws, size_t ws_size,
                              hipStream_t stream) {
    const float* x    = (const float*)d_in[0];
    const int*   ei   = (const int*)d_in[1];
    const float* W1l  = (const float*)d_in[2];
    const float* b1   = (const float*)d_in[3];
    const float* W1r  = (const float*)d_in[4];
    const float* W2l  = (const float*)d_in[5];
    const float* b2   = (const float*)d_in[6];
    const float* W2r  = (const float*)d_in[7];
    float* out = (float*)d_out;

    const int E = N_EDGES;
    const int N = N_NODES;
    const int* srcI = ei;
    const int* dstI = ei + E;

    // workspace layout (bytes)
    char* w = (char*)d_ws;
    int*            cnt     = (int*)(w + 0);                   // 200000
    int*            total   = (int*)(w + 200000);              // 4 (memset with cnt)
    int*            row_ptr = (int*)(w + 204800);              // 200000
    int*            col     = (int*)(w + 409600);              // 2400000
    __hip_bfloat16* W1t     = (__hip_bfloat16*)(w + 2818048);  // [256][256]
    __hip_bfloat16* W2t     = (__hip_bfloat16*)(w + 2949120);  // [256][256]
    int*            cursor  = (int*)(w + 3080192);             // 200000
    __hip_bfloat16* A1      = (__hip_bfloat16*)(w + 3280896);  // [50000][256]
    __hip_bfloat16* h_bf    = (__hip_bfloat16*)(w + 28880896); // [50000][256]
    unsigned char*  hp_f8   = (unsigned char*)(w + 54480896);  // [50000][128] fp8
    float*          pre     = (float*)(w + 67280896);          // [50000][128] fp32

    // ---- zero cnt+total, then fused prep (+degree count) ----
    hipMemsetAsync(cnt, 0, 200004, stream);
    prep<<<PB_X, 256, 0, stream>>>(x, A1, W1l, W1r, W2l, W2r, W1t, W2t, dstI, cnt);

    // ---- CSR build ----
    assign_offsets<<<(N + 255) / 256, 256, 0, stream>>>(cnt, row_ptr, cursor, total, N);
    fill_csr<<<(E + 255) / 256, 256, 0, stream>>>(srcI, dstI, cursor, col, E);

    // ---- layer 1 ----
    aggregate_bf16<<<(N + 15) / 16, 256, 0, stream>>>(
        A1 + 128, 256, row_ptr, cnt, col, A1, 256, N);
    {
        dim3 grid((N + GBM - 1) / GBM, HID_C / GBN);
        gemm_mfma<<<grid, 256, 0, stream>>>(A1, 256, W1t, b1,
                                            h_bf, nullptr, nullptr, N, 256, 0);
    }

    // ---- layer 2 fused projection (y0 -> hp fp8, y1 -> pre fp32) ----
    {
        dim3 grid((N + GBM - 1) / GBM, 2);
        gemm_mfma<<<grid, 256, 0, stream>>>(h_bf, 256, W2t, b2,
                                            nullptr, hp_f8, pre, N, 256, 1);
    }
    // ---- final: out = pre + mean(hp) ----
    aggregate_fp8_final<<<(N + 15) / 16, 256, 0, stream>>>(
        hp_f8, row_ptr, cnt, col, out, pre, N);
}

// Round 12
// 232.214 us; speedup vs baseline: 1.0397x; 1.0111x over previous
//
#include <hip/hip_runtime.h>
#include <hip/hip_bf16.h>

// GraphSAGE 2-layer forward, MI355X. R12 = R11 + single-pass dual-output
// gemm2 (h staged ONCE; waves 0-1 -> hp fp8, waves 2-3 -> pre fp32+b2).

#define N_NODES 50000
#define IN_C    128
#define HID_C   256
#define OUT_C   128
#define N_EDGES 600000

// prep block partition: count first (latency-bound), then streaming
#define PB_CNT  2344                 // ceil(600000/256)
#define PB_W1   (PB_CNT + 256)       // 2600
#define PB_W2   (PB_W1 + 256)        // 2856
#define PB_X    (PB_W2 + 6250)       // 9106 total

typedef __attribute__((ext_vector_type(8))) short short8;   // 8 bf16 (16B)
typedef __attribute__((ext_vector_type(4))) float f32x4;
typedef __attribute__((ext_vector_type(2))) float f32x2;

__device__ __forceinline__ float bf2f(short s) {
    union { unsigned u; float f; } c;
    c.u = ((unsigned)(unsigned short)s) << 16;
    return c.f;
}
__device__ __forceinline__ unsigned f2fp8(float v) {
    return (unsigned)__builtin_amdgcn_cvt_pk_fp8_f32(v, v, 0, false) & 0xffu;
}
// accumulate 4 fp8 bytes (one u32) into a[0..3]
__device__ __forceinline__ void acc_fp8x4(float* a, unsigned u) {
    f32x2 lo = __builtin_amdgcn_cvt_pk_f32_fp8(u, false);
    f32x2 hi = __builtin_amdgcn_cvt_pk_f32_fp8(u, true);
    a[0] += lo[0]; a[1] += lo[1]; a[2] += hi[0]; a[3] += hi[1];
}

// ---------------- fused prep (+ degree count) ----------------
__global__ __launch_bounds__(256) void prep(
    const float* __restrict__ x, __hip_bfloat16* __restrict__ A1,
    const float* __restrict__ W1l, const float* __restrict__ W1r,
    const float* __restrict__ W2l, const float* __restrict__ W2r,
    __hip_bfloat16* __restrict__ W1t, __hip_bfloat16* __restrict__ W2t,
    const int* __restrict__ dstI, int* __restrict__ cnt) {
    int b = blockIdx.x;
    if (b < PB_CNT) {
        int e = b * 256 + threadIdx.x;
        if (e < N_EDGES) atomicAdd(&cnt[dstI[e]], 1);
    } else if (b < PB_W1) {
        int reg = b - PB_CNT;
        int half = reg >> 7;
        int t = (reg & 127) * 256 + threadIdx.x;
        int k = t >> 8, n = t & 255;
        const float* src = half ? W1r : W1l;
        W1t[n * 256 + half * 128 + k] = __float2bfloat16(src[t]);
    } else if (b < PB_W2) {
        int reg = b - PB_W1;
        int half = reg >> 7;
        int t = (reg & 127) * 256 + threadIdx.x;
        int k = t >> 7, n = t & 127;
        const float* src = half ? W2r : W2l;
        W2t[(size_t)(half * 128 + n) * 256 + k] = __float2bfloat16(src[t]);
    } else {
        int t = (b - PB_W2) * 256 + threadIdx.x;
        if (t >= N_NODES * 32) return;
        int row = t >> 5, c = (t & 31) * 4;
        float4 v = *(const float4*)(x + (size_t)row * 128 + c);
        __hip_bfloat16* d = A1 + (size_t)row * 256 + 128 + c;
        __hip_bfloat162 p0, p1;
        p0.x = __float2bfloat16(v.x); p0.y = __float2bfloat16(v.y);
        p1.x = __float2bfloat16(v.z); p1.y = __float2bfloat16(v.w);
        *(__hip_bfloat162*)d = p0;
        *(__hip_bfloat162*)(d + 2) = p1;
    }
}

// ---------------- CSR build ----------------
__global__ __launch_bounds__(256) void assign_offsets(
    const int* __restrict__ cnt, int* __restrict__ row_ptr,
    int* __restrict__ cursor, int* __restrict__ total, int n) {
    __shared__ int tmp[256];
    __shared__ int sbase;
    int t = threadIdx.x, g = blockIdx.x * 256 + t;
    int v = (g < n) ? cnt[g] : 0;
    tmp[t] = v; __syncthreads();
    for (int off = 1; off < 256; off <<= 1) {
        int u = (t >= off) ? tmp[t - off] : 0;
        __syncthreads();
        tmp[t] += u;
        __syncthreads();
    }
    if (t == 255) sbase = atomicAdd(total, tmp[255]);
    __syncthreads();
    if (g < n) {
        int e = sbase + tmp[t] - v;
        row_ptr[g] = e;
        cursor[g] = e;
    }
}

__global__ void fill_csr(const int* __restrict__ srcI, const int* __restrict__ dstI,
                         int* __restrict__ cursor, int* __restrict__ col, int E) {
    int e = blockIdx.x * blockDim.x + threadIdx.x;
    if (e < E) {
        int pos = atomicAdd(&cursor[dstI[e]], 1);
        col[pos] = srcI[e];
    }
}

// ---------------- layer-1 mean aggregation (bf16 gather, R9 form) ----------------
__global__ __launch_bounds__(256) void aggregate_bf16(
    const __hip_bfloat16* __restrict__ feat, int featStride,
    const int* __restrict__ row_ptr, const int* __restrict__ deg,
    const int* __restrict__ col,
    __hip_bfloat16* __restrict__ outp, int outStride, int nNodes) {
    int node = blockIdx.x * 16 + (threadIdx.x >> 4);
    int sl   = threadIdx.x & 15;
    if (node >= nNodes) return;
    int beg = row_ptr[node];
    int d   = deg[node];
    const __hip_bfloat16* base = feat + sl * 8;
    float a[8];
    #pragma unroll
    for (int c = 0; c < 8; ++c) a[c] = 0.f;

    short8 v0, v1, v2, v3;
    int j = 0;
    if (d >= 4) {
        int s0 = col[beg + 0], s1 = col[beg + 1];
        int s2 = col[beg + 2], s3 = col[beg + 3];
        v0 = *(const short8*)(base + (size_t)s0 * featStride);
        v1 = *(const short8*)(base + (size_t)s1 * featStride);
        v2 = *(const short8*)(base + (size_t)s2 * featStride);
        v3 = *(const short8*)(base + (size_t)s3 * featStride);
        for (; j + 8 <= d; j += 4) {
            int t0 = col[beg + j + 4], t1 = col[beg + j + 5];
            int t2 = col[beg + j + 6], t3 = col[beg + j + 7];
            short8 w0 = *(const short8*)(base + (size_t)t0 * featStride);
            short8 w1 = *(const short8*)(base + (size_t)t1 * featStride);
            short8 w2 = *(const short8*)(base + (size_t)t2 * featStride);
            short8 w3 = *(const short8*)(base + (size_t)t3 * featStride);
            #pragma unroll
            for (int c = 0; c < 8; ++c)
                a[c] += (bf2f(v0[c]) + bf2f(v1[c])) + (bf2f(v2[c]) + bf2f(v3[c]));
            v0 = w0; v1 = w1; v2 = w2; v3 = w3;
        }
        #pragma unroll
        for (int c = 0; c < 8; ++c)
            a[c] += (bf2f(v0[c]) + bf2f(v1[c])) + (bf2f(v2[c]) + bf2f(v3[c]));
        j += 4;
    }
    int rem = d - j;
    if (rem > 0) {
        int s0 = col[beg + j];
        int s1 = (rem > 1) ? col[beg + j + 1] : s0;
        int s2 = (rem > 2) ? col[beg + j + 2] : s0;
        short8 t0 = *(const short8*)(base + (size_t)s0 * featStride);
        short8 t1 = *(const short8*)(base + (size_t)s1 * featStride);
        short8 t2 = *(const short8*)(base + (size_t)s2 * featStride);
        #pragma unroll
        for (int c = 0; c < 8; ++c) a[c] += bf2f(t0[c]);
        if (rem > 1) {
            #pragma unroll
            for (int c = 0; c < 8; ++c) a[c] += bf2f(t1[c]);
        }
        if (rem > 2) {
            #pragma unroll
            for (int c = 0; c < 8; ++c) a[c] += bf2f(t2[c]);
        }
    }

    float inv = 1.f / (float)max(d, 1);
    __hip_bfloat16* o = outp + (size_t)node * outStride + sl * 8;
    short8 q;
    #pragma unroll
    for (int c = 0; c < 8; ++c) {
        union { __hip_bfloat16 b; short s; } cv;
        cv.b = __float2bfloat16(a[c] * inv);
        q[c] = cv.s;
    }
    *(short8*)o = q;
}

// ---------------- final aggregation (fp8 gather, R9 form) ----------------
__global__ __launch_bounds__(256) void aggregate_fp8_final(
    const unsigned char* __restrict__ feat,   // [n][128] fp8 e4m3
    const int* __restrict__ row_ptr, const int* __restrict__ deg,
    const int* __restrict__ col,
    float* __restrict__ outp, const float* __restrict__ pre, int nNodes) {
    int node = blockIdx.x * 16 + (threadIdx.x >> 4);
    int sl   = threadIdx.x & 15;
    if (node >= nNodes) return;
    int beg = row_ptr[node];
    int d   = deg[node];
    const unsigned char* base = feat + sl * 8;
    float a[8];
    #pragma unroll
    for (int c = 0; c < 8; ++c) a[c] = 0.f;

    uint2 v0, v1, v2, v3;
    int j = 0;
    if (d >= 4) {
        int s0 = col[beg + 0], s1 = col[beg + 1];
        int s2 = col[beg + 2], s3 = col[beg + 3];
        v0 = *(const uint2*)(base + (size_t)s0 * 128);
        v1 = *(const uint2*)(base + (size_t)s1 * 128);
        v2 = *(const uint2*)(base + (size_t)s2 * 128);
        v3 = *(const uint2*)(base + (size_t)s3 * 128);
        for (; j + 8 <= d; j += 4) {
            int t0 = col[beg + j + 4], t1 = col[beg + j + 5];
            int t2 = col[beg + j + 6], t3 = col[beg + j + 7];
            uint2 w0 = *(const uint2*)(base + (size_t)t0 * 128);
            uint2 w1 = *(const uint2*)(base + (size_t)t1 * 128);
            uint2 w2 = *(const uint2*)(base + (size_t)t2 * 128);
            uint2 w3 = *(const uint2*)(base + (size_t)t3 * 128);
            acc_fp8x4(a,     v0.x); acc_fp8x4(a,     v1.x);
            acc_fp8x4(a,     v2.x); acc_fp8x4(a,     v3.x);
            acc_fp8x4(a + 4, v0.y); acc_fp8x4(a + 4, v1.y);
            acc_fp8x4(a + 4, v2.y); acc_fp8x4(a + 4, v3.y);
            v0 = w0; v1 = w1; v2 = w2; v3 = w3;
        }
        acc_fp8x4(a,     v0.x); acc_fp8x4(a,     v1.x);
        acc_fp8x4(a,     v2.x); acc_fp8x4(a,     v3.x);
        acc_fp8x4(a + 4, v0.y); acc_fp8x4(a + 4, v1.y);
        acc_fp8x4(a + 4, v2.y); acc_fp8x4(a + 4, v3.y);
        j += 4;
    }
    for (; j < d; ++j) {
        uint2 v = *(const uint2*)(base + (size_t)col[beg + j] * 128);
        acc_fp8x4(a, v.x);
        acc_fp8x4(a + 4, v.y);
    }

    float inv = 1.f / (float)max(d, 1);
    const float* pp = pre + (size_t)node * 128 + sl * 8;
    float* op = outp + (size_t)node * 128 + sl * 8;
    float4 p0 = *(const float4*)pp;
    float4 p1 = *(const float4*)(pp + 4);
    *(float4*)op       = make_float4(a[0] * inv + p0.x, a[1] * inv + p0.y,
                                     a[2] * inv + p0.z, a[3] * inv + p0.w);
    *(float4*)(op + 4) = make_float4(a[4] * inv + p1.x, a[5] * inv + p1.y,
                                     a[6] * inv + p1.z, a[7] * inv + p1.w);
}

// ---------------- layer-1 bf16 MFMA GEMM (128x128 tile) ----------------
// outBf = relu(A@Bt^T + bias), row stride 256 bf16; LDS-repacked epilogue.

#define GBM 128
#define GBN 128
#define GBK 64
#define EP_STRIDE_BF 132     // bf16 elems: 264 B stride, 2-way max conflict

__device__ __forceinline__ void gload16(const void* g, void* l) {
    typedef const __attribute__((address_space(1))) unsigned int* gp_t;
    typedef __attribute__((address_space(3))) unsigned int* lp_t;
    __builtin_amdgcn_global_load_lds((gp_t)g, (lp_t)l, 16, 0, 0);
}

__global__ __launch_bounds__(256) void gemm_mfma(
    const __hip_bfloat16* __restrict__ A, int lda,
    const __hip_bfloat16* __restrict__ Bt,
    const float* __restrict__ bias,
    __hip_bfloat16* __restrict__ outBf,
    int M, int K) {
    __shared__ char sm[GBM * EP_STRIDE_BF * 2];     // 33 KB; staging uses first 32 KB
    __hip_bfloat16* Als = (__hip_bfloat16*)sm;
    __hip_bfloat16* Bls = (__hip_bfloat16*)(sm + GBM * GBK * 2);

    int tid  = threadIdx.x;
    int wave = tid >> 6, lane = tid & 63;
    int wm = wave >> 1, wn = wave & 1;
    int mb = blockIdx.x * GBM, nb = blockIdx.y * GBN;

    int srow_base = wave * 32;
    int lrow = lane >> 3;
    int pch  = lane & 7;

    f32x4 acc[4][4];
    #pragma unroll
    for (int i = 0; i < 4; ++i)
        #pragma unroll
        for (int j = 0; j < 4; ++j)
            acc[i][j] = (f32x4){0.f, 0.f, 0.f, 0.f};

    for (int kt = 0; kt < K; kt += GBK) {
        #pragma unroll
        for (int t = 0; t < 4; ++t) {
            int rloc = srow_base + t * 8 + lrow;
            int lch  = pch ^ (rloc & 7);
            int ga_row = mb + rloc; if (ga_row >= M) ga_row = M - 1;
            const __hip_bfloat16* ga = A + (size_t)ga_row * lda + kt + lch * 8;
            gload16(ga, &Als[(srow_base + t * 8) * GBK]);
            const __hip_bfloat16* gb = Bt + (size_t)(nb + rloc) * K + kt + lch * 8;
            gload16(gb, &Bls[(srow_base + t * 8) * GBK]);
        }
        __syncthreads();

        #pragma unroll
        for (int ks = 0; ks < GBK; ks += 32) {
            int chunkL = (ks >> 3) + (lane >> 4);
            short8 af[4], bf[4];
            #pragma unroll
            for (int i = 0; i < 4; ++i) {
                int row = wm * 64 + i * 16 + (lane & 15);
                int pc  = chunkL ^ (row & 7);
                af[i] = *(const short8*)&Als[row * GBK + pc * 8];
            }
            #pragma unroll
            for (int j = 0; j < 4; ++j) {
                int row = wn * 64 + j * 16 + (lane & 15);
                int pc  = chunkL ^ (row & 7);
                bf[j] = *(const short8*)&Bls[row * GBK + pc * 8];
            }
            #pragma unroll
            for (int i = 0; i < 4; ++i)
                #pragma unroll
                for (int j = 0; j < 4; ++j)
                    acc[i][j] = __builtin_amdgcn_mfma_f32_16x16x32_bf16(
                        af[i], bf[j], acc[i][j], 0, 0, 0);
        }
        __syncthreads();
    }

    // epilogue: C/D layout col=lane&15, row=(lane>>4)*4+reg
    int cn[4];
    float bc[4];
    __hip_bfloat16* sb = (__hip_bfloat16*)sm;
    #pragma unroll
    for (int j = 0; j < 4; ++j) {
        cn[j] = wn * 64 + j * 16 + (lane & 15);
        bc[j] = bias[nb + cn[j]];
    }
    #pragma unroll
    for (int i = 0; i < 4; ++i)
        #pragma unroll
        for (int r = 0; r < 4; ++r) {
            int lr = wm * 64 + i * 16 + (lane >> 4) * 4 + r;
            #pragma unroll
            for (int j = 0; j < 4; ++j)
                sb[lr * EP_STRIDE_BF + cn[j]] =
                    __float2bfloat16(fmaxf(acc[i][j][r] + bc[j], 0.f));
        }
    __syncthreads();
    #pragma unroll
    for (int it = 0; it < 8; ++it) {
        int chunk = it * 256 + tid;          // 0..2047, 16B each
        int lr  = chunk >> 4;                // 16 chunks per 256B data row
        int lcB = (chunk & 15) * 16;
        int grow = mb + lr;
        if (grow < M)
            *(float4*)((char*)outBf + (size_t)grow * 512 + nb * 2 + lcB) =
                *(const float4*)((const char*)sb + lr * (EP_STRIDE_BF * 2) + lcB);
    }
}

// ---------------- layer-2 fused GEMM: single pass, dual output ----------------
// A = h [M][256]; Bt = W2t [256][256] (rows 0..127 -> hp fp8, 128..255 -> pre).
// GBM2=64 rows/block, all 256 output cols in one block (h staged ONCE).
// Wave w computes cols w*64..w*64+63 for all 64 rows.
#define GBM2 64

__global__ __launch_bounds__(256) void gemm2_fused(
    const __hip_bfloat16* __restrict__ A,
    const __hip_bfloat16* __restrict__ Bt,
    const float* __restrict__ b2,
    unsigned char* __restrict__ outF8,       // hp fp8 [M][128]
    float* __restrict__ outF,                // pre fp32 [M][128]
    int M) {
    __shared__ __hip_bfloat16 Als[GBM2 * GBK];   // 8 KB
    __shared__ __hip_bfloat16 Bls[256 * GBK];    // 32 KB

    int tid  = threadIdx.x;
    int wave = tid >> 6, lane = tid & 63;
    int mb = blockIdx.x * GBM2;
    int lrow = lane >> 3;
    int pch  = lane & 7;

    f32x4 acc[4][4];
    #pragma unroll
    for (int i = 0; i < 4; ++i)
        #pragma unroll
        for (int j = 0; j < 4; ++j)
            acc[i][j] = (f32x4){0.f, 0.f, 0.f, 0.f};

    for (int kt = 0; kt < 256; kt += GBK) {
        // A: 8 groups of 8 rows; wave handles groups wave*2 + {0,1}
        #pragma unroll
        for (int t = 0; t < 2; ++t) {
            int g = wave * 2 + t;
            int rloc = g * 8 + lrow;                 // 0..63
            int lch  = pch ^ (rloc & 7);
            int ga_row = mb + rloc; if (ga_row >= M) ga_row = M - 1;
            gload16(A + (size_t)ga_row * 256 + kt + lch * 8, &Als[g * 8 * GBK]);
        }
        // B: 32 groups of 8 rows; wave handles groups wave*8 + 0..7
        #pragma unroll
        for (int t = 0; t < 8; ++t) {
            int g = wave * 8 + t;
            int rloc = g * 8 + lrow;                 // 0..255
            int lch  = pch ^ (rloc & 7);
            gload16(Bt + (size_t)rloc * 256 + kt + lch * 8, &Bls[g * 8 * GBK]);
        }
        __syncthreads();

        #pragma unroll
        for (int ks = 0; ks < GBK; ks += 32) {
            int chunkL = (ks >> 3) + (lane >> 4);
            short8 af[4], bf[4];
            #pragma unroll
            for (int i = 0; i < 4; ++i) {
                int row = i * 16 + (lane & 15);          // 0..63
                int pc  = chunkL ^ (row & 7);
                af[i] = *(const short8*)&Als[row * GBK + pc * 8];
            }
            #pragma unroll
            for (int j = 0; j < 4; ++j) {
                int row = wave * 64 + j * 16 + (lane & 15);  // output col
                int pc  = chunkL ^ (row & 7);
                bf[j] = *(const short8*)&Bls[row * GBK + pc * 8];
            }
            #pragma unroll
            for (int i = 0; i < 4; ++i)
                #pragma unroll
                for (int j = 0; j < 4; ++j)
                    acc[i][j] = __builtin_amdgcn_mfma_f32_16x16x32_bf16(
                        af[i], bf[j], acc[i][j], 0, 0, 0);
        }
        __syncthreads();
    }

    // epilogue: col=lane&15 (+j*16+wave*64), row=(lane>>4)*4+reg (+i*16)
    int cn[4];
    #pragma unroll
    for (int j = 0; j < 4; ++j) cn[j] = wave * 64 + j * 16 + (lane & 15);
    if (wave < 2) {
        // cols 0..127 -> hp fp8
        #pragma unroll
        for (int i = 0; i < 4; ++i)
            #pragma unroll
            for (int r = 0; r < 4; ++r) {
                int row = mb + i * 16 + (lane >> 4) * 4 + r;
                if (row >= M) continue;
                #pragma unroll
                for (int j = 0; j < 4; ++j)
                    outF8[(size_t)row * 128 + cn[j]] = (unsigned char)f2fp8(acc[i][j][r]);
            }
    } else {
        // cols 128..255 -> pre = acc + b2
        float bc[4];
        #pragma unroll
        for (int j = 0; j < 4; ++j) bc[j] = b2[cn[j] - 128];
        #pragma unroll
        for (int i = 0; i < 4; ++i)
            #pragma unroll
            for (int r = 0; r < 4; ++r) {
                int row = mb + i * 16 + (lane >> 4) * 4 + r;
                if (row >= M) continue;
                #pragma unroll
                for (int j = 0; j < 4; ++j)
                    outF[(size_t)row * 128 + cn[j] - 128] = acc[i][j][r] + bc[j];
            }
    }
}

extern "C" void kernel_launch(void* const* d_in, const int* in_sizes, int n_in,
                              void* d_out, int out_size, void* d_ws, size_t ws_size,
                              hipStream_t stream) {
    const float* x    = (const float*)d_in[0];
    const int*   ei   = (const int*)d_in[1];
    const float* W1l  = (const float*)d_in[2];
    const float* b1   = (const float*)d_in[3];
    const float* W1r  = (const float*)d_in[4];
    const float* W2l  = (const float*)d_in[5];
    const float* b2   = (const float*)d_in[6];
    const float* W2r  = (const float*)d_in[7];
    float* out = (float*)d_out;

    const int E = N_EDGES;
    const int N = N_NODES;
    const int* srcI = ei;
    const int* dstI = ei + E;

    // workspace layout (bytes)
    char* w = (char*)d_ws;
    int*            cnt     = (int*)(w + 0);                   // 200000
    int*            total   = (int*)(w + 200000);              // 4 (memset with cnt)
    int*            row_ptr = (int*)(w + 204800);              // 200000
    int*            col     = (int*)(w + 409600);              // 2400000
    __hip_bfloat16* W1t     = (__hip_bfloat16*)(w + 2818048);  // [256][256]
    __hip_bfloat16* W2t     = (__hip_bfloat16*)(w + 2949120);  // [256][256]
    int*            cursor  = (int*)(w + 3080192);             // 200000
    __hip_bfloat16* A1      = (__hip_bfloat16*)(w + 3280896);  // [50000][256]
    __hip_bfloat16* h_bf    = (__hip_bfloat16*)(w + 28880896); // [50000][256]
    unsigned char*  hp_f8   = (unsigned char*)(w + 54480896);  // [50000][128] fp8
    float*          pre     = (float*)(w + 67280896);          // [50000][128] fp32

    // ---- zero cnt+total, then fused prep (+degree count) ----
    hipMemsetAsync(cnt, 0, 200004, stream);
    prep<<<PB_X, 256, 0, stream>>>(x, A1, W1l, W1r, W2l, W2r, W1t, W2t, dstI, cnt);

    // ---- CSR build ----
    assign_offsets<<<(N + 255) / 256, 256, 0, stream>>>(cnt, row_ptr, cursor, total, N);
    fill_csr<<<(E + 255) / 256, 256, 0, stream>>>(srcI, dstI, cursor, col, E);

    // ---- layer 1 ----
    aggregate_bf16<<<(N + 15) / 16, 256, 0, stream>>>(
        A1 + 128, 256, row_ptr, cnt, col, A1, 256, N);
    {
        dim3 grid((N + GBM - 1) / GBM, HID_C / GBN);
        gemm_mfma<<<grid, 256, 0, stream>>>(A1, 256, W1t, b1, h_bf, N, 256);
    }

    // ---- layer 2: single-pass dual output (h staged once) ----
    gemm2_fused<<<(N + GBM2 - 1) / GBM2, 256, 0, stream>>>(
        h_bf, W2t, b2, hp_f8, pre, N);

    // ---- final: out = pre + mean(hp) ----
    aggregate_fp8_final<<<(N + 15) / 16, 256, 0, stream>>>(
        hp_f8, row_ptr, cnt, col, out, pre, N);
}